// Round 8
// baseline (317.782 us; speedup 1.0000x reference)
//
#include <hip/hip_runtime.h>
#include <hip/hip_bf16.h>

using ushort_t = unsigned short;
using f32x4  = __attribute__((ext_vector_type(4))) float;
using short8 = __attribute__((ext_vector_type(8))) short;

// ---------- bf16 helpers ----------
__device__ __forceinline__ float bflo(unsigned p) {
    union { unsigned u; float f; } x; x.u = p << 16; return x.f;
}
__device__ __forceinline__ float bfhi(unsigned p) {
    union { unsigned u; float f; } x; x.u = p & 0xffff0000u; return x.f;
}
__device__ __forceinline__ ushort_t f2bf(float f) {
    __hip_bfloat16 h = __float2bfloat16(f);   // RTNE
    return *(ushort_t*)&h;
}
__device__ __forceinline__ unsigned pk2bf(float lo, float hi) {
    __hip_bfloat162 h = __float22bfloat162_rn({lo, hi});  // RTNE, packed
    return *(unsigned*)&h;
}

// ---------- combined weight prep (clf transpose dropped) ----------
__device__ __forceinline__ void tr_tile(const float* __restrict__ S, ushort_t* __restrict__ D,
                                        int K, int N, int Npad, int bx, int by,
                                        int tx, int ty, float* tile /*32*33*/)
{
    const int k0 = by * 32, n0 = bx * 32;
#pragma unroll
    for (int r = 0; r < 4; r++) {
        const int k = k0 + ty + r * 8, n = n0 + tx;
        tile[(ty + r * 8) * 33 + tx] = (k < K && n < N) ? S[(size_t)k * N + n] : 0.f;
    }
    __syncthreads();
#pragma unroll
    for (int r = 0; r < 4; r++) {
        const int n = n0 + ty + r * 8, k = k0 + tx;
        if (n < Npad && k < K) D[(size_t)n * K + k] = f2bf(tile[tx * 33 + ty + r * 8]);
    }
}

__global__ __launch_bounds__(256)
void prep_weights(const float* __restrict__ Wobj, ushort_t* __restrict__ WobjT,
                  const float* __restrict__ Wact, ushort_t* __restrict__ WactT,
                  const float* __restrict__ fc1W, ushort_t* __restrict__ fc1T,
                  const float* __restrict__ gc1W, ushort_t* __restrict__ W1t,
                  const float* __restrict__ gc3W, ushort_t* __restrict__ W3t,
                  const float* __restrict__ gc2W, ushort_t* __restrict__ W2bf,
                  const float* __restrict__ gc4W, ushort_t* __restrict__ W4bf)
{
    __shared__ float tile[32 * 33];
    const int b = blockIdx.x;
    const int t = threadIdx.x;
    const int tx = t & 31, ty = t >> 5;

    if (b < 1056) {
        const float* S; ushort_t* D; int K, N, Npad, nt, l;
        if      (b < 256)  { S = Wobj; D = WobjT; K = 512; N = 512;  Npad = 512;  nt = 16; l = b; }
        else if (b < 512)  { S = Wact; D = WactT; K = 512; N = 512;  Npad = 512;  nt = 16; l = b - 256; }
        else if (b < 1024) { S = fc1W; D = fc1T;  K = 512; N = 1024; Npad = 1024; nt = 32; l = b - 512; }
        else if (b < 1040) { S = gc1W; D = W1t;   K = 512; N = 32;   Npad = 32;   nt = 1;  l = b - 1024; }
        else               { S = gc3W; D = W3t;   K = 512; N = 32;   Npad = 32;   nt = 1;  l = b - 1040; }
        tr_tile(S, D, K, N, Npad, l % nt, l / nt, tx, ty, tile);
    } else {
        const float* S = (b < 1064) ? gc2W : gc4W;
        ushort_t* D    = (b < 1064) ? W2bf : W4bf;
        const int i = (b < 1064 ? b - 1056 : b - 1064) * 256 + t;
        const float4 x = ((const float4*)S)[2 * i];
        const float4 y = ((const float4*)S)[2 * i + 1];
        unsigned r[4] = { pk2bf(x.x, x.y), pk2bf(x.z, x.w), pk2bf(y.x, y.y), pk2bf(y.z, y.w) };
        ((uint4*)D)[i] = *(uint4*)r;
    }
}

// ---------- streaming GEMM core: A staged once in LDS, B streamed from L2 ----------
// NO barriers in the K-loop -> compiler can pipeline loads across iterations.
// K fixed 512. NI = m-tiles of 16 (ROWS = NI*16). Wave covers 128 cols (j=8).
// LDS rows are 1KB -> chunk-XOR swizzle (c ^ (row&7)) makes frag b128 reads 2-way (free).
template<int NI, typename AT>
__device__ __forceinline__ void stream_core(
    const AT* __restrict__ A, const ushort_t* __restrict__ Bt,
    const float* __restrict__ bias, ushort_t* __restrict__ C,
    int N, int bm, int n0, int row_mul, int row_add, int skip8,
    ushort_t* As)
{
    const int t = threadIdx.x;
    const int lane = t & 63, w = t >> 6;
    const int fr = lane & 15, fq = lane >> 4;
    constexpr int NCH = NI * 16 * 64;          // 8-elem chunks in the A tile

    // stage A (fp32 -> bf16 fused, or bf16 passthrough), coalesced
#pragma unroll
    for (int i = 0; i < NCH / 256; i++) {
        const int cid = i * 256 + t;
        const int row = cid >> 6, c = cid & 63;
        uint4 v;
        if constexpr (sizeof(AT) == 4) {
            const float* gp = (const float*)A + (size_t)(bm + row) * 512 + c * 8;
            const float4 p0 = *(const float4*)gp;
            const float4 p1 = *(const float4*)(gp + 4);
            unsigned rr[4] = { pk2bf(p0.x, p0.y), pk2bf(p0.z, p0.w),
                               pk2bf(p1.x, p1.y), pk2bf(p1.z, p1.w) };
            v = *(uint4*)rr;
        } else {
            v = *(const uint4*)((const ushort_t*)A + (size_t)(bm + row) * 512 + c * 8);
        }
        *(uint4*)&As[row * 512 + ((c ^ (row & 7)) * 8)] = v;
    }
    __syncthreads();   // the only barrier

    const int nw = n0 + w * 128;
    const ushort_t* Bbase = Bt + (size_t)(nw + fr) * 512 + fq * 8;

    f32x4 acc[8][NI];
#pragma unroll
    for (int j = 0; j < 8; j++)
#pragma unroll
        for (int i = 0; i < NI; i++) acc[j][i] = (f32x4){0.f, 0.f, 0.f, 0.f};

#pragma unroll 2
    for (int kk = 0; kk < 16; kk++) {
        uint4 b[8];
#pragma unroll
        for (int j = 0; j < 8; j++)
            b[j] = *(const uint4*)(Bbase + (size_t)j * 16 * 512 + kk * 32);
        short8 af[NI];
#pragma unroll
        for (int i = 0; i < NI; i++)
            af[i] = *(const short8*)&As[(i * 16 + fr) * 512 + (((kk * 4 + fq) ^ (fr & 7)) * 8)];
#pragma unroll
        for (int j = 0; j < 8; j++) {
            const short8 bfv = *(const short8*)&b[j];
#pragma unroll
            for (int i = 0; i < NI; i++)
                acc[j][i] = __builtin_amdgcn_mfma_f32_16x16x32_bf16(af[i], bfv, acc[j][i], 0, 0, 0);
        }
    }

    // epilogue: row = i*16 + fq*4 + rr, col = nw + j*16 + fr; relu always
#pragma unroll
    for (int j = 0; j < 8; j++) {
        const int n = nw + j * 16 + fr;
        const float bv = bias[n];
#pragma unroll
        for (int i = 0; i < NI; i++) {
#pragma unroll
            for (int rr = 0; rr < 4; rr++) {
                const int ml = i * 16 + fq * 4 + rr;
                if (skip8 && (ml & 15) == 8) continue;     // rows owned by act
                const int m = bm + ml;
                C[((size_t)m * row_mul + row_add) * (size_t)N + n] =
                    f2bf(fmaxf(acc[j][i][rr] + bv, 0.f));
            }
        }
    }
}

// obj (blocks 0..1023, 32 rows each) + act (blocks 1024..1087) in ONE dispatch.
// launch_bounds(256,3): 3 blocks/CU (32KB LDS x3 = 96KB), VGPR cap 168 (no spill).
__global__ __launch_bounds__(256, 3)
void gemm_objact_stream(const float* __restrict__ Ao, const ushort_t* __restrict__ Bo,
                        const float* __restrict__ bo,
                        const float* __restrict__ Aa, const ushort_t* __restrict__ Ba,
                        const float* __restrict__ ba, ushort_t* __restrict__ C)
{
    __shared__ __align__(16) ushort_t As[32 * 512];   // 32KB
    if (blockIdx.x < 1024)
        stream_core<2, float>(Ao, Bo, bo, C, 512, blockIdx.x * 32, 0, 1, 0, 1, As);
    else
        stream_core<2, float>(Aa, Ba, ba, C, 512, (blockIdx.x - 1024) * 32, 0, 16, 8, 0, As);
}

// fc1: M=2048, N=1024, K=512; 16-row tiles x 2 n-halves = 256 blocks.
__global__ __launch_bounds__(256, 4)
void gemm_fc1_stream(const ushort_t* __restrict__ A, const ushort_t* __restrict__ Bt,
                     const float* __restrict__ bias, ushort_t* __restrict__ C)
{
    __shared__ __align__(16) ushort_t As[16 * 512];   // 16KB
    const int mb = blockIdx.x >> 1, n0 = (blockIdx.x & 1) * 512;
    stream_core<1, ushort_t>(A, Bt, bias, C, 1024, mb * 16, n0, 1, 0, 0, As);
}

// ---------- graph stage: one wave per graph (unchanged) ----------
__global__ __launch_bounds__(64)
void graph_mfma(const ushort_t* __restrict__ obj,
                const ushort_t* __restrict__ W1t, const float* __restrict__ b1,
                const ushort_t* __restrict__ W2b, const float* __restrict__ b2,
                const ushort_t* __restrict__ W3t, const float* __restrict__ b3,
                const ushort_t* __restrict__ W4b, const float* __restrict__ b4,
                ushort_t* __restrict__ cbuf)
{
    __shared__ float ssb[16 * 17];
    __shared__ float adjt[16 * 20];
    __shared__ float t1s[16 * 36];
    __shared__ float t3s[16 * 36];
    __shared__ float x1s[16 * 36];
    __shared__ float y2s[16 * 36];
    __shared__ float y22s[16 * 17];
    __shared__ float a3t[16 * 20];
    __shared__ float dv[16], dv3[16], nrm[16], cA[16], cA3[16];
    __shared__ float zc1[32], zc4[32];

    const int lane = threadIdx.x;
    const int r = lane & 15, fq = lane >> 4;
    const ushort_t* xg = obj + (size_t)blockIdx.x * 8192;

    short8 xf[16];
#pragma unroll
    for (int kk = 0; kk < 16; kk++)
        xf[kk] = *(const short8*)(xg + r * 512 + kk * 32 + fq * 8);

    f32x4 sacc = (f32x4){0.f, 0.f, 0.f, 0.f};
#pragma unroll
    for (int kk = 0; kk < 16; kk++)
        sacc = __builtin_amdgcn_mfma_f32_16x16x32_bf16(xf[kk], xf[kk], sacc, 0, 0, 0);

    f32x4 a10 = (f32x4){0.f,0.f,0.f,0.f}, a11 = a10, a30 = a10, a31 = a10;
#pragma unroll
    for (int kk = 0; kk < 16; kk++) {
        const short8 w10 = *(const short8*)(W1t + (size_t)(r)      * 512 + kk * 32 + fq * 8);
        const short8 w11 = *(const short8*)(W1t + (size_t)(16 + r) * 512 + kk * 32 + fq * 8);
        const short8 w30 = *(const short8*)(W3t + (size_t)(r)      * 512 + kk * 32 + fq * 8);
        const short8 w31 = *(const short8*)(W3t + (size_t)(16 + r) * 512 + kk * 32 + fq * 8);
        a10 = __builtin_amdgcn_mfma_f32_16x16x32_bf16(xf[kk], w10, a10, 0, 0, 0);
        a11 = __builtin_amdgcn_mfma_f32_16x16x32_bf16(xf[kk], w11, a11, 0, 0, 0);
        a30 = __builtin_amdgcn_mfma_f32_16x16x32_bf16(xf[kk], w30, a30, 0, 0, 0);
        a31 = __builtin_amdgcn_mfma_f32_16x16x32_bf16(xf[kk], w31, a31, 0, 0, 0);
    }

#pragma unroll
    for (int i = 0; i < 4; i++) {
        const int m = fq * 4 + i;
        ssb[m * 17 + r] = sacc[i];
        t1s[m * 36 + r]      = a10[i];
        t1s[m * 36 + 16 + r] = a11[i];
        t3s[m * 36 + r]      = a30[i];
        t3s[m * 36 + 16 + r] = a31[i];
    }
    __syncthreads();

    if (lane < 16) {
        float m = ssb[lane * 17];
#pragma unroll
        for (int j = 1; j < 16; j++) m = fmaxf(m, ssb[lane * 17 + j]);
        float s = 0.f;
#pragma unroll
        for (int j = 0; j < 16; j++) {
            const float e = expf(ssb[lane * 17 + j] - m);
            ssb[lane * 17 + j] = e; s += e;
        }
        dv[lane] = rsqrtf(s);
    }
    __syncthreads();

    {
        const float di = dv[r];
#pragma unroll
        for (int p = 0; p < 4; p++) {
            const int j = fq * 4 + p;
            adjt[j * 20 + r] = ssb[r * 17 + j] * di * dv[j];
        }
    }
    __syncthreads();

    if (lane < 16) {
        float s = 0.f;
#pragma unroll
        for (int i = 0; i < 16; i++) s += adjt[lane * 20 + i];
        cA[lane] = s;
    }

    {
        const int c = lane & 31, hi = lane >> 5;
        const float bb1 = b1[c], bb3 = b3[c];
        float ax[8], ay[8];
#pragma unroll
        for (int i = 0; i < 8; i++) { ax[i] = bb1; ay[i] = bb3; }
#pragma unroll
        for (int j = 0; j < 16; j++) {
            const float t1v = t1s[j * 36 + c], t3v = t3s[j * 36 + c];
            const float4 p = *(const float4*)&adjt[j * 20 + hi * 8];
            const float4 q = *(const float4*)&adjt[j * 20 + hi * 8 + 4];
            ax[0] = fmaf(p.x, t1v, ax[0]); ax[1] = fmaf(p.y, t1v, ax[1]);
            ax[2] = fmaf(p.z, t1v, ax[2]); ax[3] = fmaf(p.w, t1v, ax[3]);
            ax[4] = fmaf(q.x, t1v, ax[4]); ax[5] = fmaf(q.y, t1v, ax[5]);
            ax[6] = fmaf(q.z, t1v, ax[6]); ax[7] = fmaf(q.w, t1v, ax[7]);
            ay[0] = fmaf(p.x, t3v, ay[0]); ay[1] = fmaf(p.y, t3v, ay[1]);
            ay[2] = fmaf(p.z, t3v, ay[2]); ay[3] = fmaf(p.w, t3v, ay[3]);
            ay[4] = fmaf(q.x, t3v, ay[4]); ay[5] = fmaf(q.y, t3v, ay[5]);
            ay[6] = fmaf(q.z, t3v, ay[6]); ay[7] = fmaf(q.w, t3v, ay[7]);
        }
#pragma unroll
        for (int i = 0; i < 8; i++) {
            x1s[(hi * 8 + i) * 36 + c] = fmaxf(ax[i], 0.f);
            y2s[(hi * 8 + i) * 36 + c] = fmaxf(ay[i], 0.f);
        }
    }
    __syncthreads();

    {
        const int i2 = lane >> 2, j0 = (lane & 3) * 4;
        float a4[4] = {0.f, 0.f, 0.f, 0.f};
#pragma unroll
        for (int k4 = 0; k4 < 8; k4++) {
            const float4 yi = *(const float4*)&y2s[i2 * 36 + k4 * 4];
#pragma unroll
            for (int p = 0; p < 4; p++) {
                const float4 yj = *(const float4*)&y2s[(j0 + p) * 36 + k4 * 4];
                a4[p] = fmaf(yi.x, yj.x, a4[p]); a4[p] = fmaf(yi.y, yj.y, a4[p]);
                a4[p] = fmaf(yi.z, yj.z, a4[p]); a4[p] = fmaf(yi.w, yj.w, a4[p]);
            }
        }
#pragma unroll
        for (int p = 0; p < 4; p++) y22s[i2 * 17 + j0 + p] = a4[p];
    }
    __syncthreads();

    if (lane < 16) {
        float sq = 0.f;
#pragma unroll
        for (int j = 0; j < 16; j++) { const float v = y22s[lane * 17 + j]; sq = fmaf(v, v, sq); }
        nrm[lane] = sqrtf(sq);
    }
    __syncthreads();

    {
        const float ni = nrm[r];
#pragma unroll
        for (int p = 0; p < 4; p++) {
            const int j = fq * 4 + p;
            a3t[j * 20 + r] = 1.0f + y22s[r * 17 + j] / (ni * nrm[j]);
        }
    }
    __syncthreads();

    if (lane < 16) {
        float s = 0.f;
#pragma unroll
        for (int j = 0; j < 16; j++) s += a3t[j * 20 + lane];
        dv3[lane] = rsqrtf(s);
    }
    __syncthreads();

    if (lane < 16) {
        float s = 0.f;
#pragma unroll
        for (int i = 0; i < 16; i++) s = fmaf(a3t[lane * 20 + i], dv3[i], s);
        cA3[lane] = s * dv3[lane];
    }
    __syncthreads();

    if (lane < 32) {
        float s1 = 0.f, s4 = 0.f;
#pragma unroll
        for (int j = 0; j < 16; j++) {
            s1 = fmaf(cA[j],  x1s[j * 36 + lane], s1);
            s4 = fmaf(cA3[j], y2s[j * 36 + lane], s4);
        }
        zc1[lane] = s1; zc4[lane] = s4;
    }
    __syncthreads();

    {
        float om[8] = {0,0,0,0,0,0,0,0};
#pragma unroll
        for (int m = 0; m < 16; m++) {
            const uint4 q = *(const uint4*)(xg + m * 512 + lane * 8);
            om[0] += bflo(q.x); om[1] += bfhi(q.x);
            om[2] += bflo(q.y); om[3] += bfhi(q.y);
            om[4] += bflo(q.z); om[5] += bfhi(q.z);
            om[6] += bflo(q.w); om[7] += bfhi(q.w);
        }
        float gm[8] = {0,0,0,0,0,0,0,0};
        for (int k = 0; k < 32; k++) {
            const float z1 = zc1[k], z4 = zc4[k];
            const uint4 w2 = *(const uint4*)(W2b + (size_t)k * 512 + lane * 8);
            const uint4 w4 = *(const uint4*)(W4b + (size_t)k * 512 + lane * 8);
            gm[0] = fmaf(z1, bflo(w2.x), gm[0]); gm[0] = fmaf(z4, bflo(w4.x), gm[0]);
            gm[1] = fmaf(z1, bfhi(w2.x), gm[1]); gm[1] = fmaf(z4, bfhi(w4.x), gm[1]);
            gm[2] = fmaf(z1, bflo(w2.y), gm[2]); gm[2] = fmaf(z4, bflo(w4.y), gm[2]);
            gm[3] = fmaf(z1, bfhi(w2.y), gm[3]); gm[3] = fmaf(z4, bfhi(w4.y), gm[3]);
            gm[4] = fmaf(z1, bflo(w2.z), gm[4]); gm[4] = fmaf(z4, bflo(w4.z), gm[4]);
            gm[5] = fmaf(z1, bfhi(w2.z), gm[5]); gm[5] = fmaf(z4, bfhi(w4.z), gm[5]);
            gm[6] = fmaf(z1, bflo(w2.w), gm[6]); gm[6] = fmaf(z4, bflo(w4.w), gm[6]);
            gm[7] = fmaf(z1, bfhi(w2.w), gm[7]); gm[7] = fmaf(z4, bfhi(w4.w), gm[7]);
        }
        const float4 b2a = *(const float4*)&b2[lane * 8];
        const float4 b2b = *(const float4*)&b2[lane * 8 + 4];
        const float4 b4a = *(const float4*)&b4[lane * 8];
        const float4 b4b = *(const float4*)&b4[lane * 8 + 4];
        const float bs[8] = { b2a.x + b4a.x, b2a.y + b4a.y, b2a.z + b4a.z, b2a.w + b4a.w,
                              b2b.x + b4b.x, b2b.y + b4b.y, b2b.z + b4b.z, b2b.w + b4b.w };
        ushort_t pk[8];
#pragma unroll
        for (int c = 0; c < 8; c++) {
            const float gmean = 0.5f * bs[c] + gm[c] * (1.0f / 32.0f);
            const float feat  = 0.5f * (om[c] * 0.0625f + gmean);
            pk[c] = f2bf(fmaxf(feat, 0.f));
        }
        *(uint4*)(cbuf + (size_t)blockIdx.x * 512 + lane * 8) = *(uint4*)pk;
    }
}

// ---------- cmean[32,1024] = mean over T=64 of c2[2048,1024] ----------
__global__ __launch_bounds__(256)
void mean_c2(const ushort_t* __restrict__ c2, float* __restrict__ cmean)
{
    const int idx = blockIdx.x * 256 + threadIdx.x;
    const int n = idx >> 10, k = idx & 1023;
    const ushort_t* p = c2 + (size_t)n * 64 * 1024 + k;
    float s = 0.f;
#pragma unroll 8
    for (int tt = 0; tt < 64; tt++) {
        union { unsigned u; float f; } x; x.u = ((unsigned)p[tt * 1024]) << 16;
        s += x.f;
    }
    cmean[idx] = s * (1.0f / 64.0f);
}

// ---------- tiny clf (mean-before-affine), reads ORIGINAL fp32 clf_W ----------
__global__ __launch_bounds__(256)
void clf_small(const float* __restrict__ cmean, const float* __restrict__ W,
               const float* __restrict__ clf_b, float* __restrict__ out)
{
    const int t = threadIdx.x;
    const int n = t & 31, jo = t >> 5;
    const int j = blockIdx.x * 8 + jo;
    const int jc = j < 500 ? j : 499;
    const float4* cm = (const float4*)(cmean + (size_t)n * 1024);
    float acc = 0.f;
#pragma unroll 4
    for (int k4 = 0; k4 < 256; k4++) {
        const float4 c = cm[k4];                       // coalesced-ish, L2-hot
        const float* wp = W + (size_t)(k4 * 4) * 500 + jc;  // broadcast across the 32 n-lanes
        acc = fmaf(c.x, wp[0],    acc);
        acc = fmaf(c.y, wp[500],  acc);
        acc = fmaf(c.z, wp[1000], acc);
        acc = fmaf(c.w, wp[1500], acc);
    }
    if (j < 500) out[(size_t)n * 500 + j] = acc + clf_b[j];
}

// ---------- launcher ----------
extern "C" void kernel_launch(void* const* d_in, const int* in_sizes, int n_in,
                              void* d_out, int out_size, void* d_ws, size_t ws_size,
                              hipStream_t stream)
{
    const float* object_raw = (const float*)d_in[0];
    const float* action_raw = (const float*)d_in[1];
    const float* W_obj = (const float*)d_in[2];
    const float* b_obj = (const float*)d_in[3];
    const float* W_act = (const float*)d_in[4];
    const float* b_act = (const float*)d_in[5];
    const float* gc1_W = (const float*)d_in[6];
    const float* gc1_b = (const float*)d_in[7];
    const float* gc2_W = (const float*)d_in[8];
    const float* gc2_b = (const float*)d_in[9];
    const float* gc3_W = (const float*)d_in[10];
    const float* gc3_b = (const float*)d_in[11];
    const float* gc4_W = (const float*)d_in[12];
    const float* gc4_b = (const float*)d_in[13];
    const float* fc1_W = (const float*)d_in[14];
    const float* fc1_b = (const float*)d_in[15];
    const float* clf_W = (const float*)d_in[16];
    const float* clf_b = (const float*)d_in[17];

    char* ws = (char*)d_ws;
    const size_t MB = 1024 * 1024;
    ushort_t* obj_bf = (ushort_t*)(ws);                       // 32 MB
    ushort_t* cbuf   = (ushort_t*)(ws + 32 * MB);             // 2 MB
    ushort_t* c2     = (ushort_t*)(ws + 34 * MB);             // 4 MB
    float*    cmean  = (float*)   (ws + 38 * MB);             // 128 KB
    ushort_t* WobjT  = (ushort_t*)(ws + 39 * MB);             // 512 KB
    ushort_t* WactT  = (ushort_t*)(ws + 39 * MB + 512 * 1024);
    ushort_t* fc1T   = (ushort_t*)(ws + 40 * MB);             // 1 MB
    ushort_t* W1t    = (ushort_t*)(ws + 41 * MB);
    ushort_t* W3t    = (ushort_t*)(ws + 41 * MB + 32 * 1024);
    ushort_t* W2bf   = (ushort_t*)(ws + 41 * MB + 64 * 1024);
    ushort_t* W4bf   = (ushort_t*)(ws + 41 * MB + 96 * 1024);

    // 1. weight prep (clf transpose eliminated)
    prep_weights<<<dim3(1072), 256, 0, stream>>>(
        W_obj, WobjT, W_act, WactT, fc1_W, fc1T,
        gc1_W, W1t, gc3_W, W3t, gc2_W, W2bf, gc4_W, W4bf);

    // 2. obj + act, barrier-free streaming GEMM, one dispatch
    gemm_objact_stream<<<dim3(1088), 256, 0, stream>>>(
        object_raw, WobjT, b_obj, action_raw, WactT, b_act, obj_bf);

    // 3. graph stage: one wave per graph
    graph_mfma<<<dim3(2048), 64, 0, stream>>>(
        obj_bf, W1t, gc1_b, W2bf, gc2_b, W3t, gc3_b, W4bf, gc4_b, cbuf);

    // 4. c2 = relu(cbuf @ fc1_W + fc1_b), streaming GEMM
    gemm_fc1_stream<<<dim3(256), 256, 0, stream>>>(cbuf, fc1T, fc1_b, c2);

    // 5. cmean = mean over T
    mean_c2<<<dim3(128), 256, 0, stream>>>(c2, cmean);

    // 6. out = cmean @ clf_W + clf_b
    clf_small<<<dim3(63), 256, 0, stream>>>(cmean, clf_W, clf_b, (float*)d_out);
}

// Round 9
// 287.988 us; speedup vs baseline: 1.1035x; 1.1035x over previous
//
#include <hip/hip_runtime.h>
#include <hip/hip_bf16.h>

using ushort_t = unsigned short;
using f32x4  = __attribute__((ext_vector_type(4))) float;
using short8 = __attribute__((ext_vector_type(8))) short;

// ---------- bf16 helpers ----------
__device__ __forceinline__ float bflo(unsigned p) {
    union { unsigned u; float f; } x; x.u = p << 16; return x.f;
}
__device__ __forceinline__ float bfhi(unsigned p) {
    union { unsigned u; float f; } x; x.u = p & 0xffff0000u; return x.f;
}
__device__ __forceinline__ ushort_t f2bf(float f) {
    __hip_bfloat16 h = __float2bfloat16(f);   // RTNE
    return *(ushort_t*)&h;
}
__device__ __forceinline__ unsigned pk2bf(float lo, float hi) {
    __hip_bfloat162 h = __float22bfloat162_rn({lo, hi});  // RTNE, packed
    return *(unsigned*)&h;
}

// ---------- combined weight prep (no clf transpose) ----------
__device__ __forceinline__ void tr_tile(const float* __restrict__ S, ushort_t* __restrict__ D,
                                        int K, int N, int Npad, int bx, int by,
                                        int tx, int ty, float* tile /*32*33*/)
{
    const int k0 = by * 32, n0 = bx * 32;
#pragma unroll
    for (int r = 0; r < 4; r++) {
        const int k = k0 + ty + r * 8, n = n0 + tx;
        tile[(ty + r * 8) * 33 + tx] = (k < K && n < N) ? S[(size_t)k * N + n] : 0.f;
    }
    __syncthreads();
#pragma unroll
    for (int r = 0; r < 4; r++) {
        const int n = n0 + ty + r * 8, k = k0 + tx;
        if (n < Npad && k < K) D[(size_t)n * K + k] = f2bf(tile[tx * 33 + ty + r * 8]);
    }
}

__global__ __launch_bounds__(256)
void prep_weights(const float* __restrict__ Wobj, ushort_t* __restrict__ WobjT,
                  const float* __restrict__ Wact, ushort_t* __restrict__ WactT,
                  const float* __restrict__ fc1W, ushort_t* __restrict__ fc1T,
                  const float* __restrict__ gc1W, ushort_t* __restrict__ W1t,
                  const float* __restrict__ gc3W, ushort_t* __restrict__ W3t,
                  const float* __restrict__ gc2W, ushort_t* __restrict__ W2bf,
                  const float* __restrict__ gc4W, ushort_t* __restrict__ W4bf)
{
    __shared__ float tile[32 * 33];
    const int b = blockIdx.x;
    const int t = threadIdx.x;
    const int tx = t & 31, ty = t >> 5;

    if (b < 1056) {
        const float* S; ushort_t* D; int K, N, Npad, nt, l;
        if      (b < 256)  { S = Wobj; D = WobjT; K = 512; N = 512;  Npad = 512;  nt = 16; l = b; }
        else if (b < 512)  { S = Wact; D = WactT; K = 512; N = 512;  Npad = 512;  nt = 16; l = b - 256; }
        else if (b < 1024) { S = fc1W; D = fc1T;  K = 512; N = 1024; Npad = 1024; nt = 32; l = b - 512; }
        else if (b < 1040) { S = gc1W; D = W1t;   K = 512; N = 32;   Npad = 32;   nt = 1;  l = b - 1024; }
        else               { S = gc3W; D = W3t;   K = 512; N = 32;   Npad = 32;   nt = 1;  l = b - 1040; }
        tr_tile(S, D, K, N, Npad, l % nt, l / nt, tx, ty, tile);
    } else {
        const float* S = (b < 1064) ? gc2W : gc4W;
        ushort_t* D    = (b < 1064) ? W2bf : W4bf;
        const int i = (b < 1064 ? b - 1056 : b - 1064) * 256 + t;
        const float4 x = ((const float4*)S)[2 * i];
        const float4 y = ((const float4*)S)[2 * i + 1];
        unsigned r[4] = { pk2bf(x.x, x.y), pk2bf(x.z, x.w), pk2bf(y.x, y.y), pk2bf(y.z, y.w) };
        ((uint4*)D)[i] = *(uint4*)r;
    }
}

// ---------- obj GEMM: A-resident streaming (r7-proven: NI=4 + B ping-pong) ----------
// C[m,n] = relu(A[m,:] @ WobjT[n,:] + b[n]), M=32768, N=K=512.
// 64 A-rows staged once in 64KB LDS (fp32->bf16 fused, chunk-XOR swizzle).
// B streamed from L2 with explicit ping-pong; rows m%16==8 skipped (act-owned).
__global__ __launch_bounds__(256, 2)
void gemm_obj_stream(const float* __restrict__ A, const ushort_t* __restrict__ Bt,
                     const float* __restrict__ bias, ushort_t* __restrict__ C)
{
    __shared__ __align__(16) ushort_t As[64 * 512];   // 64KB
    const int t = threadIdx.x;
    const int lane = t & 63, w = t >> 6;
    const int bm = blockIdx.x * 64;
    const int fr = lane & 15, fq = lane >> 4;

#pragma unroll
    for (int i = 0; i < 16; i++) {
        const int flat = i * 256 + t;
        const int row = flat >> 6, c = flat & 63;
        const float* gp = A + (size_t)(bm + row) * 512 + c * 8;
        const float4 p0 = *(const float4*)gp;
        const float4 p1 = *(const float4*)(gp + 4);
        unsigned rr[4] = { pk2bf(p0.x, p0.y), pk2bf(p0.z, p0.w),
                           pk2bf(p1.x, p1.y), pk2bf(p1.z, p1.w) };
        *(uint4*)&As[row * 512 + ((c ^ (row & 7)) * 8)] = *(uint4*)rr;
    }
    __syncthreads();   // the only barrier

    const int nw = w * 128;
    const ushort_t* Bbase = Bt + (size_t)(nw + fr) * 512 + fq * 8;

    f32x4 acc[8][4];
#pragma unroll
    for (int j = 0; j < 8; j++)
#pragma unroll
        for (int i = 0; i < 4; i++) acc[j][i] = (f32x4){0.f, 0.f, 0.f, 0.f};

    uint4 bA[8], bB[8];
#pragma unroll
    for (int j = 0; j < 8; j++) bA[j] = *(const uint4*)(Bbase + (size_t)j * 16 * 512);

    for (int kk = 0; kk < 16; kk += 2) {
        short8 af[4];
#pragma unroll
        for (int i = 0; i < 4; i++)
            af[i] = *(const short8*)&As[(i * 16 + fr) * 512 + (((kk * 4 + fq) ^ (fr & 7)) * 8)];
#pragma unroll
        for (int j = 0; j < 8; j++) {
            bB[j] = *(const uint4*)(Bbase + (size_t)j * 16 * 512 + (kk + 1) * 32);
            const short8 bf = *(const short8*)&bA[j];
#pragma unroll
            for (int i = 0; i < 4; i++)
                acc[j][i] = __builtin_amdgcn_mfma_f32_16x16x32_bf16(af[i], bf, acc[j][i], 0, 0, 0);
        }
#pragma unroll
        for (int i = 0; i < 4; i++)
            af[i] = *(const short8*)&As[(i * 16 + fr) * 512 + ((((kk + 1) * 4 + fq) ^ (fr & 7)) * 8)];
#pragma unroll
        for (int j = 0; j < 8; j++) {
            if (kk + 2 < 16)
                bA[j] = *(const uint4*)(Bbase + (size_t)j * 16 * 512 + (kk + 2) * 32);
            const short8 bf = *(const short8*)&bB[j];
#pragma unroll
            for (int i = 0; i < 4; i++)
                acc[j][i] = __builtin_amdgcn_mfma_f32_16x16x32_bf16(af[i], bf, acc[j][i], 0, 0, 0);
        }
    }

#pragma unroll
    for (int j = 0; j < 8; j++) {
        const int n = nw + j * 16 + fr;
        const float bv = bias[n];
#pragma unroll
        for (int i = 0; i < 4; i++) {
#pragma unroll
            for (int rr = 0; rr < 4; rr++) {
                const int ml = fq * 4 + rr;
                if (ml == 8) continue;
                const int m = bm + i * 16 + ml;
                C[(size_t)m * 512 + n] = f2bf(fmaxf(acc[j][i][rr] + bv, 0.f));
            }
        }
    }
}

// ---------- generic MFMA GEMM (barrier structure, proven for act + fc1) ----------
typedef __attribute__((address_space(1))) void glb_void;
typedef __attribute__((address_space(3))) void lds_void;
__device__ __forceinline__ void dma16(const void* g, void* l) {
    __builtin_amdgcn_global_load_lds((glb_void*)(unsigned long long)(uintptr_t)g,
                                     (lds_void*)(unsigned)(uintptr_t)l, 16, 0, 0);
}

template<int RELU, typename AT>
__global__ __launch_bounds__(256)
void gemm_dma(const AT* __restrict__ A, const ushort_t* __restrict__ Bt,
              const float* __restrict__ bias, ushort_t* __restrict__ C,
              int N, int K, int Nb, int row_mul, int row_add)
{
    __shared__ __align__(16) char     AsRaw[128 * 32 * sizeof(AT)];
    __shared__ __align__(16) ushort_t Bs[128 * 32];
    const int t = threadIdx.x;
    const int lane = t & 63, w = t >> 6;
    const int bm = blockIdx.y * 128, bn = blockIdx.x * 128;
    const int mb = (w & 1) * 64, nb = (w >> 1) * 64;
    const int fr = lane & 15, fq = lane >> 4;

    f32x4 acc[16];
#pragma unroll
    for (int i = 0; i < 16; i++) acc[i] = (f32x4){0.f, 0.f, 0.f, 0.f};

    const int brow = lane >> 2, bk = lane & 3;
    const int klog = bk ^ ((brow >> 1) & 3);
    const int arow = lane >> 3, ag = lane & 7;

    for (int k0 = 0; k0 < K; k0 += 32) {
        __syncthreads();
        if constexpr (sizeof(AT) == 4) {
#pragma unroll
            for (int i = 0; i < 4; i++) {
                const int grp = w * 4 + i;
                const int row = grp * 8 + arow;
                const int gl = ag ^ (row & 7);
                dma16((const float*)A + (size_t)(bm + row) * K + k0 + gl * 4,
                      AsRaw + grp * 1024);
            }
        } else {
#pragma unroll
            for (int i = 0; i < 2; i++) {
                const int grp = w * 2 + i;
                const int row = grp * 16 + brow;
                dma16((const ushort_t*)A + (size_t)(bm + row) * K + k0 + klog * 8,
                      (ushort_t*)AsRaw + grp * 512);
            }
        }
#pragma unroll
        for (int i = 0; i < 2; i++) {
            const int grp = w * 2 + i;
            const int row = grp * 16 + brow;
            dma16(Bt + (size_t)(bn + row) * K + k0 + klog * 8, Bs + grp * 512);
        }
        __syncthreads();

        short8 af[4], bf[4];
        if constexpr (sizeof(AT) == 4) {
#pragma unroll
            for (int i = 0; i < 4; i++) {
                const int row = mb + i * 16 + fr;
                const float* base = (const float*)AsRaw + row * 32;
                const f32x4 p0 = *(const f32x4*)(base + (((2 * fq)     ^ (fr & 7)) * 4));
                const f32x4 p1 = *(const f32x4*)(base + (((2 * fq + 1) ^ (fr & 7)) * 4));
                unsigned rr[4] = { pk2bf(p0.x, p0.y), pk2bf(p0.z, p0.w),
                                   pk2bf(p1.x, p1.y), pk2bf(p1.z, p1.w) };
                af[i] = *(short8*)rr;
            }
        } else {
#pragma unroll
            for (int i = 0; i < 4; i++) {
                const int row = mb + i * 16 + fr;
                af[i] = *(const short8*)((const ushort_t*)AsRaw + row * 32 + (fq ^ ((fr >> 1) & 3)) * 8);
            }
        }
#pragma unroll
        for (int j = 0; j < 4; j++) {
            const int row = nb + j * 16 + fr;
            bf[j] = *(const short8*)(Bs + row * 32 + (fq ^ ((fr >> 1) & 3)) * 8);
        }
#pragma unroll
        for (int i = 0; i < 4; i++)
#pragma unroll
            for (int j = 0; j < 4; j++)
                acc[i * 4 + j] = __builtin_amdgcn_mfma_f32_16x16x32_bf16(
                    af[i], bf[j], acc[i * 4 + j], 0, 0, 0);
    }

#pragma unroll
    for (int j = 0; j < 4; j++) {
        const int n = bn + nb + j * 16 + fr;
        const float bv = (n < Nb) ? bias[n] : 0.f;
#pragma unroll
        for (int i = 0; i < 4; i++) {
            const f32x4 a = acc[i * 4 + j];
#pragma unroll
            for (int r = 0; r < 4; r++) {
                const int m = bm + mb + i * 16 + fq * 4 + r;
                float v = a[r] + bv;
                if (RELU) v = fmaxf(v, 0.f);
                C[((size_t)m * row_mul + row_add) * (size_t)N + n] = f2bf(v);
            }
        }
    }
}

// ---------- graph stage: one wave per graph (r4-proven, unchanged) ----------
__global__ __launch_bounds__(64)
void graph_mfma(const ushort_t* __restrict__ obj,
                const ushort_t* __restrict__ W1t, const float* __restrict__ b1,
                const ushort_t* __restrict__ W2b, const float* __restrict__ b2,
                const ushort_t* __restrict__ W3t, const float* __restrict__ b3,
                const ushort_t* __restrict__ W4b, const float* __restrict__ b4,
                ushort_t* __restrict__ cbuf)
{
    __shared__ float ssb[16 * 17];
    __shared__ float adjt[16 * 20];
    __shared__ float t1s[16 * 36];
    __shared__ float t3s[16 * 36];
    __shared__ float x1s[16 * 36];
    __shared__ float y2s[16 * 36];
    __shared__ float y22s[16 * 17];
    __shared__ float a3t[16 * 20];
    __shared__ float dv[16], dv3[16], nrm[16], cA[16], cA3[16];
    __shared__ float zc1[32], zc4[32];

    const int lane = threadIdx.x;
    const int r = lane & 15, fq = lane >> 4;
    const ushort_t* xg = obj + (size_t)blockIdx.x * 8192;

    short8 xf[16];
#pragma unroll
    for (int kk = 0; kk < 16; kk++)
        xf[kk] = *(const short8*)(xg + r * 512 + kk * 32 + fq * 8);

    f32x4 sacc = (f32x4){0.f, 0.f, 0.f, 0.f};
#pragma unroll
    for (int kk = 0; kk < 16; kk++)
        sacc = __builtin_amdgcn_mfma_f32_16x16x32_bf16(xf[kk], xf[kk], sacc, 0, 0, 0);

    f32x4 a10 = (f32x4){0.f,0.f,0.f,0.f}, a11 = a10, a30 = a10, a31 = a10;
#pragma unroll
    for (int kk = 0; kk < 16; kk++) {
        const short8 w10 = *(const short8*)(W1t + (size_t)(r)      * 512 + kk * 32 + fq * 8);
        const short8 w11 = *(const short8*)(W1t + (size_t)(16 + r) * 512 + kk * 32 + fq * 8);
        const short8 w30 = *(const short8*)(W3t + (size_t)(r)      * 512 + kk * 32 + fq * 8);
        const short8 w31 = *(const short8*)(W3t + (size_t)(16 + r) * 512 + kk * 32 + fq * 8);
        a10 = __builtin_amdgcn_mfma_f32_16x16x32_bf16(xf[kk], w10, a10, 0, 0, 0);
        a11 = __builtin_amdgcn_mfma_f32_16x16x32_bf16(xf[kk], w11, a11, 0, 0, 0);
        a30 = __builtin_amdgcn_mfma_f32_16x16x32_bf16(xf[kk], w30, a30, 0, 0, 0);
        a31 = __builtin_amdgcn_mfma_f32_16x16x32_bf16(xf[kk], w31, a31, 0, 0, 0);
    }

#pragma unroll
    for (int i = 0; i < 4; i++) {
        const int m = fq * 4 + i;
        ssb[m * 17 + r] = sacc[i];
        t1s[m * 36 + r]      = a10[i];
        t1s[m * 36 + 16 + r] = a11[i];
        t3s[m * 36 + r]      = a30[i];
        t3s[m * 36 + 16 + r] = a31[i];
    }
    __syncthreads();

    if (lane < 16) {
        float m = ssb[lane * 17];
#pragma unroll
        for (int j = 1; j < 16; j++) m = fmaxf(m, ssb[lane * 17 + j]);
        float s = 0.f;
#pragma unroll
        for (int j = 0; j < 16; j++) {
            const float e = expf(ssb[lane * 17 + j] - m);
            ssb[lane * 17 + j] = e; s += e;
        }
        dv[lane] = rsqrtf(s);
    }
    __syncthreads();

    {
        const float di = dv[r];
#pragma unroll
        for (int p = 0; p < 4; p++) {
            const int j = fq * 4 + p;
            adjt[j * 20 + r] = ssb[r * 17 + j] * di * dv[j];
        }
    }
    __syncthreads();

    if (lane < 16) {
        float s = 0.f;
#pragma unroll
        for (int i = 0; i < 16; i++) s += adjt[lane * 20 + i];
        cA[lane] = s;
    }

    {
        const int c = lane & 31, hi = lane >> 5;
        const float bb1 = b1[c], bb3 = b3[c];
        float ax[8], ay[8];
#pragma unroll
        for (int i = 0; i < 8; i++) { ax[i] = bb1; ay[i] = bb3; }
#pragma unroll
        for (int j = 0; j < 16; j++) {
            const float t1v = t1s[j * 36 + c], t3v = t3s[j * 36 + c];
            const float4 p = *(const float4*)&adjt[j * 20 + hi * 8];
            const float4 q = *(const float4*)&adjt[j * 20 + hi * 8 + 4];
            ax[0] = fmaf(p.x, t1v, ax[0]); ax[1] = fmaf(p.y, t1v, ax[1]);
            ax[2] = fmaf(p.z, t1v, ax[2]); ax[3] = fmaf(p.w, t1v, ax[3]);
            ax[4] = fmaf(q.x, t1v, ax[4]); ax[5] = fmaf(q.y, t1v, ax[5]);
            ax[6] = fmaf(q.z, t1v, ax[6]); ax[7] = fmaf(q.w, t1v, ax[7]);
            ay[0] = fmaf(p.x, t3v, ay[0]); ay[1] = fmaf(p.y, t3v, ay[1]);
            ay[2] = fmaf(p.z, t3v, ay[2]); ay[3] = fmaf(p.w, t3v, ay[3]);
            ay[4] = fmaf(q.x, t3v, ay[4]); ay[5] = fmaf(q.y, t3v, ay[5]);
            ay[6] = fmaf(q.z, t3v, ay[6]); ay[7] = fmaf(q.w, t3v, ay[7]);
        }
#pragma unroll
        for (int i = 0; i < 8; i++) {
            x1s[(hi * 8 + i) * 36 + c] = fmaxf(ax[i], 0.f);
            y2s[(hi * 8 + i) * 36 + c] = fmaxf(ay[i], 0.f);
        }
    }
    __syncthreads();

    {
        const int i2 = lane >> 2, j0 = (lane & 3) * 4;
        float a4[4] = {0.f, 0.f, 0.f, 0.f};
#pragma unroll
        for (int k4 = 0; k4 < 8; k4++) {
            const float4 yi = *(const float4*)&y2s[i2 * 36 + k4 * 4];
#pragma unroll
            for (int p = 0; p < 4; p++) {
                const float4 yj = *(const float4*)&y2s[(j0 + p) * 36 + k4 * 4];
                a4[p] = fmaf(yi.x, yj.x, a4[p]); a4[p] = fmaf(yi.y, yj.y, a4[p]);
                a4[p] = fmaf(yi.z, yj.z, a4[p]); a4[p] = fmaf(yi.w, yj.w, a4[p]);
            }
        }
#pragma unroll
        for (int p = 0; p < 4; p++) y22s[i2 * 17 + j0 + p] = a4[p];
    }
    __syncthreads();

    if (lane < 16) {
        float sq = 0.f;
#pragma unroll
        for (int j = 0; j < 16; j++) { const float v = y22s[lane * 17 + j]; sq = fmaf(v, v, sq); }
        nrm[lane] = sqrtf(sq);
    }
    __syncthreads();

    {
        const float ni = nrm[r];
#pragma unroll
        for (int p = 0; p < 4; p++) {
            const int j = fq * 4 + p;
            a3t[j * 20 + r] = 1.0f + y22s[r * 17 + j] / (ni * nrm[j]);
        }
    }
    __syncthreads();

    if (lane < 16) {
        float s = 0.f;
#pragma unroll
        for (int j = 0; j < 16; j++) s += a3t[j * 20 + lane];
        dv3[lane] = rsqrtf(s);
    }
    __syncthreads();

    if (lane < 16) {
        float s = 0.f;
#pragma unroll
        for (int i = 0; i < 16; i++) s = fmaf(a3t[lane * 20 + i], dv3[i], s);
        cA3[lane] = s * dv3[lane];
    }
    __syncthreads();

    if (lane < 32) {
        float s1 = 0.f, s4 = 0.f;
#pragma unroll
        for (int j = 0; j < 16; j++) {
            s1 = fmaf(cA[j],  x1s[j * 36 + lane], s1);
            s4 = fmaf(cA3[j], y2s[j * 36 + lane], s4);
        }
        zc1[lane] = s1; zc4[lane] = s4;
    }
    __syncthreads();

    {
        float om[8] = {0,0,0,0,0,0,0,0};
#pragma unroll
        for (int m = 0; m < 16; m++) {
            const uint4 q = *(const uint4*)(xg + m * 512 + lane * 8);
            om[0] += bflo(q.x); om[1] += bfhi(q.x);
            om[2] += bflo(q.y); om[3] += bfhi(q.y);
            om[4] += bflo(q.z); om[5] += bfhi(q.z);
            om[6] += bflo(q.w); om[7] += bfhi(q.w);
        }
        float gm[8] = {0,0,0,0,0,0,0,0};
        for (int k = 0; k < 32; k++) {
            const float z1 = zc1[k], z4 = zc4[k];
            const uint4 w2 = *(const uint4*)(W2b + (size_t)k * 512 + lane * 8);
            const uint4 w4 = *(const uint4*)(W4b + (size_t)k * 512 + lane * 8);
            gm[0] = fmaf(z1, bflo(w2.x), gm[0]); gm[0] = fmaf(z4, bflo(w4.x), gm[0]);
            gm[1] = fmaf(z1, bfhi(w2.x), gm[1]); gm[1] = fmaf(z4, bfhi(w4.x), gm[1]);
            gm[2] = fmaf(z1, bflo(w2.y), gm[2]); gm[2] = fmaf(z4, bflo(w4.y), gm[2]);
            gm[3] = fmaf(z1, bfhi(w2.y), gm[3]); gm[3] = fmaf(z4, bfhi(w4.y), gm[3]);
            gm[4] = fmaf(z1, bflo(w2.z), gm[4]); gm[4] = fmaf(z4, bflo(w4.z), gm[4]);
            gm[5] = fmaf(z1, bfhi(w2.z), gm[5]); gm[5] = fmaf(z4, bfhi(w4.z), gm[5]);
            gm[6] = fmaf(z1, bflo(w2.w), gm[6]); gm[6] = fmaf(z4, bflo(w4.w), gm[6]);
            gm[7] = fmaf(z1, bfhi(w2.w), gm[7]); gm[7] = fmaf(z4, bfhi(w4.w), gm[7]);
        }
        const float4 b2a = *(const float4*)&b2[lane * 8];
        const float4 b2b = *(const float4*)&b2[lane * 8 + 4];
        const float4 b4a = *(const float4*)&b4[lane * 8];
        const float4 b4b = *(const float4*)&b4[lane * 8 + 4];
        const float bs[8] = { b2a.x + b4a.x, b2a.y + b4a.y, b2a.z + b4a.z, b2a.w + b4a.w,
                              b2b.x + b4b.x, b2b.y + b4b.y, b2b.z + b4b.z, b2b.w + b4b.w };
        ushort_t pk[8];
#pragma unroll
        for (int c = 0; c < 8; c++) {
            const float gmean = 0.5f * bs[c] + gm[c] * (1.0f / 32.0f);
            const float feat  = 0.5f * (om[c] * 0.0625f + gmean);
            pk[c] = f2bf(fmaxf(feat, 0.f));
        }
        *(uint4*)(cbuf + (size_t)blockIdx.x * 512 + lane * 8) = *(uint4*)pk;
    }
}

// ---------- cmean[32,1024] = mean over T=64 of c2[2048,1024] ----------
__global__ __launch_bounds__(256)
void mean_c2(const ushort_t* __restrict__ c2, float* __restrict__ cmean)
{
    const int idx = blockIdx.x * 256 + threadIdx.x;
    const int n = idx >> 10, k = idx & 1023;
    const ushort_t* p = c2 + (size_t)n * 64 * 1024 + k;
    float s = 0.f;
#pragma unroll 8
    for (int tt = 0; tt < 64; tt++) {
        union { unsigned u; float f; } x; x.u = ((unsigned)p[tt * 1024]) << 16;
        s += x.f;
    }
    cmean[idx] = s * (1.0f / 64.0f);
}

// ---------- tiny clf (mean-before-affine), reads ORIGINAL fp32 clf_W ----------
__global__ __launch_bounds__(256)
void clf_small(const float* __restrict__ cmean, const float* __restrict__ W,
               const float* __restrict__ clf_b, float* __restrict__ out)
{
    const int t = threadIdx.x;
    const int n = t & 31, jo = t >> 5;
    const int j = blockIdx.x * 8 + jo;
    const int jc = j < 500 ? j : 499;
    const float4* cm = (const float4*)(cmean + (size_t)n * 1024);
    float acc = 0.f;
#pragma unroll 4
    for (int k4 = 0; k4 < 256; k4++) {
        const float4 c = cm[k4];
        const float* wp = W + (size_t)(k4 * 4) * 500 + jc;
        acc = fmaf(c.x, wp[0],    acc);
        acc = fmaf(c.y, wp[500],  acc);
        acc = fmaf(c.z, wp[1000], acc);
        acc = fmaf(c.w, wp[1500], acc);
    }
    if (j < 500) out[(size_t)n * 500 + j] = acc + clf_b[j];
}

// ---------- launcher ----------
extern "C" void kernel_launch(void* const* d_in, const int* in_sizes, int n_in,
                              void* d_out, int out_size, void* d_ws, size_t ws_size,
                              hipStream_t stream)
{
    const float* object_raw = (const float*)d_in[0];
    const float* action_raw = (const float*)d_in[1];
    const float* W_obj = (const float*)d_in[2];
    const float* b_obj = (const float*)d_in[3];
    const float* W_act = (const float*)d_in[4];
    const float* b_act = (const float*)d_in[5];
    const float* gc1_W = (const float*)d_in[6];
    const float* gc1_b = (const float*)d_in[7];
    const float* gc2_W = (const float*)d_in[8];
    const float* gc2_b = (const float*)d_in[9];
    const float* gc3_W = (const float*)d_in[10];
    const float* gc3_b = (const float*)d_in[11];
    const float* gc4_W = (const float*)d_in[12];
    const float* gc4_b = (const float*)d_in[13];
    const float* fc1_W = (const float*)d_in[14];
    const float* fc1_b = (const float*)d_in[15];
    const float* clf_W = (const float*)d_in[16];
    const float* clf_b = (const float*)d_in[17];

    char* ws = (char*)d_ws;
    const size_t MB = 1024 * 1024;
    ushort_t* obj_bf = (ushort_t*)(ws);                       // 32 MB
    ushort_t* cbuf   = (ushort_t*)(ws + 32 * MB);             // 2 MB
    ushort_t* c2     = (ushort_t*)(ws + 34 * MB);             // 4 MB
    float*    cmean  = (float*)   (ws + 38 * MB);             // 128 KB
    ushort_t* WobjT  = (ushort_t*)(ws + 39 * MB);             // 512 KB
    ushort_t* WactT  = (ushort_t*)(ws + 39 * MB + 512 * 1024);
    ushort_t* fc1T   = (ushort_t*)(ws + 40 * MB);             // 1 MB
    ushort_t* W1t    = (ushort_t*)(ws + 41 * MB);
    ushort_t* W3t    = (ushort_t*)(ws + 41 * MB + 32 * 1024);
    ushort_t* W2bf   = (ushort_t*)(ws + 41 * MB + 64 * 1024);
    ushort_t* W4bf   = (ushort_t*)(ws + 41 * MB + 96 * 1024);

    // 1. weight prep
    prep_weights<<<dim3(1072), 256, 0, stream>>>(
        W_obj, WobjT, W_act, WactT, fc1_W, fc1T,
        gc1_W, W1t, gc3_W, W3t, gc2_W, W2bf, gc4_W, W4bf);

    // 2. obj GEMM: r7-proven barrier-free streaming (skips rows m%16==8)
    gemm_obj_stream<<<dim3(512), 256, 0, stream>>>(object_raw, WobjT, b_obj, obj_bf);

    // 3. act GEMM writes rows g*16+8 (proven gemm_dma)
    gemm_dma<1, float><<<dim3(4, 16), 256, 0, stream>>>(
        action_raw, WactT, b_act, obj_bf, 512, 512, 512, 16, 8);

    // 4. graph stage: one wave per graph
    graph_mfma<<<dim3(2048), 64, 0, stream>>>(
        obj_bf, W1t, gc1_b, W2bf, gc2_b, W3t, gc3_b, W4bf, gc4_b, cbuf);

    // 5. c2 = relu(cbuf @ fc1_W + fc1_b) (proven gemm_dma)
    gemm_dma<1, ushort_t><<<dim3(8, 16), 256, 0, stream>>>(
        cbuf, fc1T, fc1_b, c2, 1024, 512, 1024, 1, 0);

    // 6. cmean = mean over T
    mean_c2<<<dim3(128), 256, 0, stream>>>(c2, cmean);

    // 7. out = cmean @ clf_W + clf_b
    clf_small<<<dim3(63), 256, 0, stream>>>(cmean, clf_W, clf_b, (float*)d_out);
}

// Round 10
// 247.874 us; speedup vs baseline: 1.2820x; 1.1618x over previous
//
#include <hip/hip_runtime.h>
#include <hip/hip_bf16.h>

using ushort_t = unsigned short;
using f32x4  = __attribute__((ext_vector_type(4))) float;
using short8 = __attribute__((ext_vector_type(8))) short;

// ---------- bf16 helpers ----------
__device__ __forceinline__ float bflo(unsigned p) {
    union { unsigned u; float f; } x; x.u = p << 16; return x.f;
}
__device__ __forceinline__ float bfhi(unsigned p) {
    union { unsigned u; float f; } x; x.u = p & 0xffff0000u; return x.f;
}
__device__ __forceinline__ ushort_t f2bf(float f) {
    __hip_bfloat16 h = __float2bfloat16(f);   // RTNE
    return *(ushort_t*)&h;
}
__device__ __forceinline__ unsigned pk2bf(float lo, float hi) {
    __hip_bfloat162 h = __float22bfloat162_rn({lo, hi});  // RTNE, packed
    return *(unsigned*)&h;
}

// ---------- combined weight prep (unchanged from r9) ----------
__device__ __forceinline__ void tr_tile(const float* __restrict__ S, ushort_t* __restrict__ D,
                                        int K, int N, int Npad, int bx, int by,
                                        int tx, int ty, float* tile /*32*33*/)
{
    const int k0 = by * 32, n0 = bx * 32;
#pragma unroll
    for (int r = 0; r < 4; r++) {
        const int k = k0 + ty + r * 8, n = n0 + tx;
        tile[(ty + r * 8) * 33 + tx] = (k < K && n < N) ? S[(size_t)k * N + n] : 0.f;
    }
    __syncthreads();
#pragma unroll
    for (int r = 0; r < 4; r++) {
        const int n = n0 + ty + r * 8, k = k0 + tx;
        if (n < Npad && k < K) D[(size_t)n * K + k] = f2bf(tile[tx * 33 + ty + r * 8]);
    }
}

__global__ __launch_bounds__(256)
void prep_weights(const float* __restrict__ Wobj, ushort_t* __restrict__ WobjT,
                  const float* __restrict__ Wact, ushort_t* __restrict__ WactT,
                  const float* __restrict__ fc1W, ushort_t* __restrict__ fc1T,
                  const float* __restrict__ gc1W, ushort_t* __restrict__ W1t,
                  const float* __restrict__ gc3W, ushort_t* __restrict__ W3t,
                  const float* __restrict__ gc2W, ushort_t* __restrict__ W2bf,
                  const float* __restrict__ gc4W, ushort_t* __restrict__ W4bf)
{
    __shared__ float tile[32 * 33];
    const int b = blockIdx.x;
    const int t = threadIdx.x;
    const int tx = t & 31, ty = t >> 5;

    if (b < 1056) {
        const float* S; ushort_t* D; int K, N, Npad, nt, l;
        if      (b < 256)  { S = Wobj; D = WobjT; K = 512; N = 512;  Npad = 512;  nt = 16; l = b; }
        else if (b < 512)  { S = Wact; D = WactT; K = 512; N = 512;  Npad = 512;  nt = 16; l = b - 256; }
        else if (b < 1024) { S = fc1W; D = fc1T;  K = 512; N = 1024; Npad = 1024; nt = 32; l = b - 512; }
        else if (b < 1040) { S = gc1W; D = W1t;   K = 512; N = 32;   Npad = 32;   nt = 1;  l = b - 1024; }
        else               { S = gc3W; D = W3t;   K = 512; N = 32;   Npad = 32;   nt = 1;  l = b - 1040; }
        tr_tile(S, D, K, N, Npad, l % nt, l / nt, tx, ty, tile);
    } else {
        const float* S = (b < 1064) ? gc2W : gc4W;
        ushort_t* D    = (b < 1064) ? W2bf : W4bf;
        const int i = (b < 1064 ? b - 1056 : b - 1064) * 256 + t;
        const float4 x = ((const float4*)S)[2 * i];
        const float4 y = ((const float4*)S)[2 * i + 1];
        unsigned r[4] = { pk2bf(x.x, x.y), pk2bf(x.z, x.w), pk2bf(y.x, y.y), pk2bf(y.z, y.w) };
        ((uint4*)D)[i] = *(uint4*)r;
    }
}

// ---------- obj GEMM: A-resident streaming (r7-proven: NI=4 + B ping-pong) ----------
__global__ __launch_bounds__(256, 2)
void gemm_obj_stream(const float* __restrict__ A, const ushort_t* __restrict__ Bt,
                     const float* __restrict__ bias, ushort_t* __restrict__ C)
{
    __shared__ __align__(16) ushort_t As[64 * 512];   // 64KB
    const int t = threadIdx.x;
    const int lane = t & 63, w = t >> 6;
    const int bm = blockIdx.x * 64;
    const int fr = lane & 15, fq = lane >> 4;

#pragma unroll
    for (int i = 0; i < 16; i++) {
        const int flat = i * 256 + t;
        const int row = flat >> 6, c = flat & 63;
        const float* gp = A + (size_t)(bm + row) * 512 + c * 8;
        const float4 p0 = *(const float4*)gp;
        const float4 p1 = *(const float4*)(gp + 4);
        unsigned rr[4] = { pk2bf(p0.x, p0.y), pk2bf(p0.z, p0.w),
                           pk2bf(p1.x, p1.y), pk2bf(p1.z, p1.w) };
        *(uint4*)&As[row * 512 + ((c ^ (row & 7)) * 8)] = *(uint4*)rr;
    }
    __syncthreads();   // the only barrier

    const int nw = w * 128;
    const ushort_t* Bbase = Bt + (size_t)(nw + fr) * 512 + fq * 8;

    f32x4 acc[8][4];
#pragma unroll
    for (int j = 0; j < 8; j++)
#pragma unroll
        for (int i = 0; i < 4; i++) acc[j][i] = (f32x4){0.f, 0.f, 0.f, 0.f};

    uint4 bA[8], bB[8];
#pragma unroll
    for (int j = 0; j < 8; j++) bA[j] = *(const uint4*)(Bbase + (size_t)j * 16 * 512);

    for (int kk = 0; kk < 16; kk += 2) {
        short8 af[4];
#pragma unroll
        for (int i = 0; i < 4; i++)
            af[i] = *(const short8*)&As[(i * 16 + fr) * 512 + (((kk * 4 + fq) ^ (fr & 7)) * 8)];
#pragma unroll
        for (int j = 0; j < 8; j++) {
            bB[j] = *(const uint4*)(Bbase + (size_t)j * 16 * 512 + (kk + 1) * 32);
            const short8 bf = *(const short8*)&bA[j];
#pragma unroll
            for (int i = 0; i < 4; i++)
                acc[j][i] = __builtin_amdgcn_mfma_f32_16x16x32_bf16(af[i], bf, acc[j][i], 0, 0, 0);
        }
#pragma unroll
        for (int i = 0; i < 4; i++)
            af[i] = *(const short8*)&As[(i * 16 + fr) * 512 + ((((kk + 1) * 4 + fq) ^ (fr & 7)) * 8)];
#pragma unroll
        for (int j = 0; j < 8; j++) {
            if (kk + 2 < 16)
                bA[j] = *(const uint4*)(Bbase + (size_t)j * 16 * 512 + (kk + 2) * 32);
            const short8 bf = *(const short8*)&bB[j];
#pragma unroll
            for (int i = 0; i < 4; i++)
                acc[j][i] = __builtin_amdgcn_mfma_f32_16x16x32_bf16(af[i], bf, acc[j][i], 0, 0, 0);
        }
    }

#pragma unroll
    for (int j = 0; j < 8; j++) {
        const int n = nw + j * 16 + fr;
        const float bv = bias[n];
#pragma unroll
        for (int i = 0; i < 4; i++) {
#pragma unroll
            for (int rr = 0; rr < 4; rr++) {
                const int ml = fq * 4 + rr;
                if (ml == 8) continue;
                const int m = bm + i * 16 + ml;
                C[(size_t)m * 512 + n] = f2bf(fmaxf(acc[j][i][rr] + bv, 0.f));
            }
        }
    }
}

// ---------- generic MFMA GEMM (barrier structure, proven for act + fc1) ----------
typedef __attribute__((address_space(1))) void glb_void;
typedef __attribute__((address_space(3))) void lds_void;
__device__ __forceinline__ void dma16(const void* g, void* l) {
    __builtin_amdgcn_global_load_lds((glb_void*)(unsigned long long)(uintptr_t)g,
                                     (lds_void*)(unsigned)(uintptr_t)l, 16, 0, 0);
}

template<int RELU, typename AT>
__global__ __launch_bounds__(256)
void gemm_dma(const AT* __restrict__ A, const ushort_t* __restrict__ Bt,
              const float* __restrict__ bias, ushort_t* __restrict__ C,
              int N, int K, int Nb, int row_mul, int row_add)
{
    __shared__ __align__(16) char     AsRaw[128 * 32 * sizeof(AT)];
    __shared__ __align__(16) ushort_t Bs[128 * 32];
    const int t = threadIdx.x;
    const int lane = t & 63, w = t >> 6;
    const int bm = blockIdx.y * 128, bn = blockIdx.x * 128;
    const int mb = (w & 1) * 64, nb = (w >> 1) * 64;
    const int fr = lane & 15, fq = lane >> 4;

    f32x4 acc[16];
#pragma unroll
    for (int i = 0; i < 16; i++) acc[i] = (f32x4){0.f, 0.f, 0.f, 0.f};

    const int brow = lane >> 2, bk = lane & 3;
    const int klog = bk ^ ((brow >> 1) & 3);
    const int arow = lane >> 3, ag = lane & 7;

    for (int k0 = 0; k0 < K; k0 += 32) {
        __syncthreads();
        if constexpr (sizeof(AT) == 4) {
#pragma unroll
            for (int i = 0; i < 4; i++) {
                const int grp = w * 4 + i;
                const int row = grp * 8 + arow;
                const int gl = ag ^ (row & 7);
                dma16((const float*)A + (size_t)(bm + row) * K + k0 + gl * 4,
                      AsRaw + grp * 1024);
            }
        } else {
#pragma unroll
            for (int i = 0; i < 2; i++) {
                const int grp = w * 2 + i;
                const int row = grp * 16 + brow;
                dma16((const ushort_t*)A + (size_t)(bm + row) * K + k0 + klog * 8,
                      (ushort_t*)AsRaw + grp * 512);
            }
        }
#pragma unroll
        for (int i = 0; i < 2; i++) {
            const int grp = w * 2 + i;
            const int row = grp * 16 + brow;
            dma16(Bt + (size_t)(bn + row) * K + k0 + klog * 8, Bs + grp * 512);
        }
        __syncthreads();

        short8 af[4], bf[4];
        if constexpr (sizeof(AT) == 4) {
#pragma unroll
            for (int i = 0; i < 4; i++) {
                const int row = mb + i * 16 + fr;
                const float* base = (const float*)AsRaw + row * 32;
                const f32x4 p0 = *(const f32x4*)(base + (((2 * fq)     ^ (fr & 7)) * 4));
                const f32x4 p1 = *(const f32x4*)(base + (((2 * fq + 1) ^ (fr & 7)) * 4));
                unsigned rr[4] = { pk2bf(p0.x, p0.y), pk2bf(p0.z, p0.w),
                                   pk2bf(p1.x, p1.y), pk2bf(p1.z, p1.w) };
                af[i] = *(short8*)rr;
            }
        } else {
#pragma unroll
            for (int i = 0; i < 4; i++) {
                const int row = mb + i * 16 + fr;
                af[i] = *(const short8*)((const ushort_t*)AsRaw + row * 32 + (fq ^ ((fr >> 1) & 3)) * 8);
            }
        }
#pragma unroll
        for (int j = 0; j < 4; j++) {
            const int row = nb + j * 16 + fr;
            bf[j] = *(const short8*)(Bs + row * 32 + (fq ^ ((fr >> 1) & 3)) * 8);
        }
#pragma unroll
        for (int i = 0; i < 4; i++)
#pragma unroll
            for (int j = 0; j < 4; j++)
                acc[i * 4 + j] = __builtin_amdgcn_mfma_f32_16x16x32_bf16(
                    af[i], bf[j], acc[i * 4 + j], 0, 0, 0);
    }

#pragma unroll
    for (int j = 0; j < 4; j++) {
        const int n = bn + nb + j * 16 + fr;
        const float bv = (n < Nb) ? bias[n] : 0.f;
#pragma unroll
        for (int i = 0; i < 4; i++) {
            const f32x4 a = acc[i * 4 + j];
#pragma unroll
            for (int r = 0; r < 4; r++) {
                const int m = bm + mb + i * 16 + fq * 4 + r;
                float v = a[r] + bv;
                if (RELU) v = fmaxf(v, 0.f);
                C[((size_t)m * row_mul + row_add) * (size_t)N + n] = f2bf(v);
            }
        }
    }
}

// ---------- graph stage: one wave per graph (r4-proven, unchanged) ----------
__global__ __launch_bounds__(64)
void graph_mfma(const ushort_t* __restrict__ obj,
                const ushort_t* __restrict__ W1t, const float* __restrict__ b1,
                const ushort_t* __restrict__ W2b, const float* __restrict__ b2,
                const ushort_t* __restrict__ W3t, const float* __restrict__ b3,
                const ushort_t* __restrict__ W4b, const float* __restrict__ b4,
                ushort_t* __restrict__ cbuf)
{
    __shared__ float ssb[16 * 17];
    __shared__ float adjt[16 * 20];
    __shared__ float t1s[16 * 36];
    __shared__ float t3s[16 * 36];
    __shared__ float x1s[16 * 36];
    __shared__ float y2s[16 * 36];
    __shared__ float y22s[16 * 17];
    __shared__ float a3t[16 * 20];
    __shared__ float dv[16], dv3[16], nrm[16], cA[16], cA3[16];
    __shared__ float zc1[32], zc4[32];

    const int lane = threadIdx.x;
    const int r = lane & 15, fq = lane >> 4;
    const ushort_t* xg = obj + (size_t)blockIdx.x * 8192;

    short8 xf[16];
#pragma unroll
    for (int kk = 0; kk < 16; kk++)
        xf[kk] = *(const short8*)(xg + r * 512 + kk * 32 + fq * 8);

    f32x4 sacc = (f32x4){0.f, 0.f, 0.f, 0.f};
#pragma unroll
    for (int kk = 0; kk < 16; kk++)
        sacc = __builtin_amdgcn_mfma_f32_16x16x32_bf16(xf[kk], xf[kk], sacc, 0, 0, 0);

    f32x4 a10 = (f32x4){0.f,0.f,0.f,0.f}, a11 = a10, a30 = a10, a31 = a10;
#pragma unroll
    for (int kk = 0; kk < 16; kk++) {
        const short8 w10 = *(const short8*)(W1t + (size_t)(r)      * 512 + kk * 32 + fq * 8);
        const short8 w11 = *(const short8*)(W1t + (size_t)(16 + r) * 512 + kk * 32 + fq * 8);
        const short8 w30 = *(const short8*)(W3t + (size_t)(r)      * 512 + kk * 32 + fq * 8);
        const short8 w31 = *(const short8*)(W3t + (size_t)(16 + r) * 512 + kk * 32 + fq * 8);
        a10 = __builtin_amdgcn_mfma_f32_16x16x32_bf16(xf[kk], w10, a10, 0, 0, 0);
        a11 = __builtin_amdgcn_mfma_f32_16x16x32_bf16(xf[kk], w11, a11, 0, 0, 0);
        a30 = __builtin_amdgcn_mfma_f32_16x16x32_bf16(xf[kk], w30, a30, 0, 0, 0);
        a31 = __builtin_amdgcn_mfma_f32_16x16x32_bf16(xf[kk], w31, a31, 0, 0, 0);
    }

#pragma unroll
    for (int i = 0; i < 4; i++) {
        const int m = fq * 4 + i;
        ssb[m * 17 + r] = sacc[i];
        t1s[m * 36 + r]      = a10[i];
        t1s[m * 36 + 16 + r] = a11[i];
        t3s[m * 36 + r]      = a30[i];
        t3s[m * 36 + 16 + r] = a31[i];
    }
    __syncthreads();

    if (lane < 16) {
        float m = ssb[lane * 17];
#pragma unroll
        for (int j = 1; j < 16; j++) m = fmaxf(m, ssb[lane * 17 + j]);
        float s = 0.f;
#pragma unroll
        for (int j = 0; j < 16; j++) {
            const float e = expf(ssb[lane * 17 + j] - m);
            ssb[lane * 17 + j] = e; s += e;
        }
        dv[lane] = rsqrtf(s);
    }
    __syncthreads();

    {
        const float di = dv[r];
#pragma unroll
        for (int p = 0; p < 4; p++) {
            const int j = fq * 4 + p;
            adjt[j * 20 + r] = ssb[r * 17 + j] * di * dv[j];
        }
    }
    __syncthreads();

    if (lane < 16) {
        float s = 0.f;
#pragma unroll
        for (int i = 0; i < 16; i++) s += adjt[lane * 20 + i];
        cA[lane] = s;
    }

    {
        const int c = lane & 31, hi = lane >> 5;
        const float bb1 = b1[c], bb3 = b3[c];
        float ax[8], ay[8];
#pragma unroll
        for (int i = 0; i < 8; i++) { ax[i] = bb1; ay[i] = bb3; }
#pragma unroll
        for (int j = 0; j < 16; j++) {
            const float t1v = t1s[j * 36 + c], t3v = t3s[j * 36 + c];
            const float4 p = *(const float4*)&adjt[j * 20 + hi * 8];
            const float4 q = *(const float4*)&adjt[j * 20 + hi * 8 + 4];
            ax[0] = fmaf(p.x, t1v, ax[0]); ax[1] = fmaf(p.y, t1v, ax[1]);
            ax[2] = fmaf(p.z, t1v, ax[2]); ax[3] = fmaf(p.w, t1v, ax[3]);
            ax[4] = fmaf(q.x, t1v, ax[4]); ax[5] = fmaf(q.y, t1v, ax[5]);
            ax[6] = fmaf(q.z, t1v, ax[6]); ax[7] = fmaf(q.w, t1v, ax[7]);
            ay[0] = fmaf(p.x, t3v, ay[0]); ay[1] = fmaf(p.y, t3v, ay[1]);
            ay[2] = fmaf(p.z, t3v, ay[2]); ay[3] = fmaf(p.w, t3v, ay[3]);
            ay[4] = fmaf(q.x, t3v, ay[4]); ay[5] = fmaf(q.y, t3v, ay[5]);
            ay[6] = fmaf(q.z, t3v, ay[6]); ay[7] = fmaf(q.w, t3v, ay[7]);
        }
#pragma unroll
        for (int i = 0; i < 8; i++) {
            x1s[(hi * 8 + i) * 36 + c] = fmaxf(ax[i], 0.f);
            y2s[(hi * 8 + i) * 36 + c] = fmaxf(ay[i], 0.f);
        }
    }
    __syncthreads();

    {
        const int i2 = lane >> 2, j0 = (lane & 3) * 4;
        float a4[4] = {0.f, 0.f, 0.f, 0.f};
#pragma unroll
        for (int k4 = 0; k4 < 8; k4++) {
            const float4 yi = *(const float4*)&y2s[i2 * 36 + k4 * 4];
#pragma unroll
            for (int p = 0; p < 4; p++) {
                const float4 yj = *(const float4*)&y2s[(j0 + p) * 36 + k4 * 4];
                a4[p] = fmaf(yi.x, yj.x, a4[p]); a4[p] = fmaf(yi.y, yj.y, a4[p]);
                a4[p] = fmaf(yi.z, yj.z, a4[p]); a4[p] = fmaf(yi.w, yj.w, a4[p]);
            }
        }
#pragma unroll
        for (int p = 0; p < 4; p++) y22s[i2 * 17 + j0 + p] = a4[p];
    }
    __syncthreads();

    if (lane < 16) {
        float sq = 0.f;
#pragma unroll
        for (int j = 0; j < 16; j++) { const float v = y22s[lane * 17 + j]; sq = fmaf(v, v, sq); }
        nrm[lane] = sqrtf(sq);
    }
    __syncthreads();

    {
        const float ni = nrm[r];
#pragma unroll
        for (int p = 0; p < 4; p++) {
            const int j = fq * 4 + p;
            a3t[j * 20 + r] = 1.0f + y22s[r * 17 + j] / (ni * nrm[j]);
        }
    }
    __syncthreads();

    if (lane < 16) {
        float s = 0.f;
#pragma unroll
        for (int j = 0; j < 16; j++) s += a3t[j * 20 + lane];
        dv3[lane] = rsqrtf(s);
    }
    __syncthreads();

    if (lane < 16) {
        float s = 0.f;
#pragma unroll
        for (int i = 0; i < 16; i++) s = fmaf(a3t[lane * 20 + i], dv3[i], s);
        cA3[lane] = s * dv3[lane];
    }
    __syncthreads();

    if (lane < 32) {
        float s1 = 0.f, s4 = 0.f;
#pragma unroll
        for (int j = 0; j < 16; j++) {
            s1 = fmaf(cA[j],  x1s[j * 36 + lane], s1);
            s4 = fmaf(cA3[j], y2s[j * 36 + lane], s4);
        }
        zc1[lane] = s1; zc4[lane] = s4;
    }
    __syncthreads();

    {
        float om[8] = {0,0,0,0,0,0,0,0};
#pragma unroll
        for (int m = 0; m < 16; m++) {
            const uint4 q = *(const uint4*)(xg + m * 512 + lane * 8);
            om[0] += bflo(q.x); om[1] += bfhi(q.x);
            om[2] += bflo(q.y); om[3] += bfhi(q.y);
            om[4] += bflo(q.z); om[5] += bfhi(q.z);
            om[6] += bflo(q.w); om[7] += bfhi(q.w);
        }
        float gm[8] = {0,0,0,0,0,0,0,0};
        for (int k = 0; k < 32; k++) {
            const float z1 = zc1[k], z4 = zc4[k];
            const uint4 w2 = *(const uint4*)(W2b + (size_t)k * 512 + lane * 8);
            const uint4 w4 = *(const uint4*)(W4b + (size_t)k * 512 + lane * 8);
            gm[0] = fmaf(z1, bflo(w2.x), gm[0]); gm[0] = fmaf(z4, bflo(w4.x), gm[0]);
            gm[1] = fmaf(z1, bfhi(w2.x), gm[1]); gm[1] = fmaf(z4, bfhi(w4.x), gm[1]);
            gm[2] = fmaf(z1, bflo(w2.y), gm[2]); gm[2] = fmaf(z4, bflo(w4.y), gm[2]);
            gm[3] = fmaf(z1, bfhi(w2.y), gm[3]); gm[3] = fmaf(z4, bfhi(w4.y), gm[3]);
            gm[4] = fmaf(z1, bflo(w2.z), gm[4]); gm[4] = fmaf(z4, bflo(w4.z), gm[4]);
            gm[5] = fmaf(z1, bfhi(w2.z), gm[5]); gm[5] = fmaf(z4, bfhi(w4.z), gm[5]);
            gm[6] = fmaf(z1, bflo(w2.w), gm[6]); gm[6] = fmaf(z4, bflo(w4.w), gm[6]);
            gm[7] = fmaf(z1, bfhi(w2.w), gm[7]); gm[7] = fmaf(z4, bfhi(w4.w), gm[7]);
        }
        const float4 b2a = *(const float4*)&b2[lane * 8];
        const float4 b2b = *(const float4*)&b2[lane * 8 + 4];
        const float4 b4a = *(const float4*)&b4[lane * 8];
        const float4 b4b = *(const float4*)&b4[lane * 8 + 4];
        const float bs[8] = { b2a.x + b4a.x, b2a.y + b4a.y, b2a.z + b4a.z, b2a.w + b4a.w,
                              b2b.x + b4b.x, b2b.y + b4b.y, b2b.z + b4b.z, b2b.w + b4b.w };
        ushort_t pk[8];
#pragma unroll
        for (int c = 0; c < 8; c++) {
            const float gmean = 0.5f * bs[c] + gm[c] * (1.0f / 32.0f);
            const float feat  = 0.5f * (om[c] * 0.0625f + gmean);
            pk[c] = f2bf(fmaxf(feat, 0.f));
        }
        *(uint4*)(cbuf + (size_t)blockIdx.x * 512 + lane * 8) = *(uint4*)pk;
    }
}

// ---------- cmean[32,1024] = mean over T=64 of c2[2048,1024] ----------
__global__ __launch_bounds__(256)
void mean_c2(const ushort_t* __restrict__ c2, float* __restrict__ cmean)
{
    const int idx = blockIdx.x * 256 + threadIdx.x;
    const int n = idx >> 10, k = idx & 1023;
    const ushort_t* p = c2 + (size_t)n * 64 * 1024 + k;
    float s = 0.f;
#pragma unroll 8
    for (int tt = 0; tt < 64; tt++) {
        union { unsigned u; float f; } x; x.u = ((unsigned)p[tt * 1024]) << 16;
        s += x.f;
    }
    cmean[idx] = s * (1.0f / 64.0f);
}

// ---------- clf GEMV: one block per column j, 32 n x 8 k-parts ----------
// W column loads are wave-broadcast (32 n-lanes share the address); 500 blocks
// give ~2 blocks/CU (vs r9's 63-block / 1-wave-per-CU latency disaster).
__global__ __launch_bounds__(256)
void clf_col(const float* __restrict__ cmean, const float* __restrict__ W,
             const float* __restrict__ clf_b, float* __restrict__ out)
{
    __shared__ float red[8][33];
    const int j = blockIdx.x;            // 0..499
    const int t = threadIdx.x;
    const int n = t & 31, kp = t >> 5;   // 8 k-parts x 128
    const float* cm = cmean + (size_t)n * 1024 + kp * 128;
    const float* wp = W + (size_t)kp * 128 * 500 + j;
    float acc = 0.f;
#pragma unroll
    for (int k = 0; k < 128; k += 4) {
        const float4 c = *(const float4*)(cm + k);
        acc = fmaf(c.x, wp[(size_t)(k + 0) * 500], acc);
        acc = fmaf(c.y, wp[(size_t)(k + 1) * 500], acc);
        acc = fmaf(c.z, wp[(size_t)(k + 2) * 500], acc);
        acc = fmaf(c.w, wp[(size_t)(k + 3) * 500], acc);
    }
    red[kp][n] = acc;
    __syncthreads();
    if (t < 32) {
        float s = red[0][t];
#pragma unroll
        for (int p = 1; p < 8; p++) s += red[p][t];
        out[(size_t)t * 500 + j] = s + clf_b[j];
    }
}

// ---------- launcher ----------
extern "C" void kernel_launch(void* const* d_in, const int* in_sizes, int n_in,
                              void* d_out, int out_size, void* d_ws, size_t ws_size,
                              hipStream_t stream)
{
    const float* object_raw = (const float*)d_in[0];
    const float* action_raw = (const float*)d_in[1];
    const float* W_obj = (const float*)d_in[2];
    const float* b_obj = (const float*)d_in[3];
    const float* W_act = (const float*)d_in[4];
    const float* b_act = (const float*)d_in[5];
    const float* gc1_W = (const float*)d_in[6];
    const float* gc1_b = (const float*)d_in[7];
    const float* gc2_W = (const float*)d_in[8];
    const float* gc2_b = (const float*)d_in[9];
    const float* gc3_W = (const float*)d_in[10];
    const float* gc3_b = (const float*)d_in[11];
    const float* gc4_W = (const float*)d_in[12];
    const float* gc4_b = (const float*)d_in[13];
    const float* fc1_W = (const float*)d_in[14];
    const float* fc1_b = (const float*)d_in[15];
    const float* clf_W = (const float*)d_in[16];
    const float* clf_b = (const float*)d_in[17];

    char* ws = (char*)d_ws;
    const size_t MB = 1024 * 1024;
    ushort_t* obj_bf = (ushort_t*)(ws);                       // 32 MB
    ushort_t* cbuf   = (ushort_t*)(ws + 32 * MB);             // 2 MB
    ushort_t* c2     = (ushort_t*)(ws + 34 * MB);             // 4 MB
    float*    cmean  = (float*)   (ws + 38 * MB);             // 128 KB
    ushort_t* WobjT  = (ushort_t*)(ws + 39 * MB);             // 512 KB
    ushort_t* WactT  = (ushort_t*)(ws + 39 * MB + 512 * 1024);
    ushort_t* fc1T   = (ushort_t*)(ws + 40 * MB);             // 1 MB
    ushort_t* W1t    = (ushort_t*)(ws + 41 * MB);
    ushort_t* W3t    = (ushort_t*)(ws + 41 * MB + 32 * 1024);
    ushort_t* W2bf   = (ushort_t*)(ws + 41 * MB + 64 * 1024);
    ushort_t* W4bf   = (ushort_t*)(ws + 41 * MB + 96 * 1024);

    // 1. weight prep
    prep_weights<<<dim3(1072), 256, 0, stream>>>(
        W_obj, WobjT, W_act, WactT, fc1_W, fc1T,
        gc1_W, W1t, gc3_W, W3t, gc2_W, W2bf, gc4_W, W4bf);

    // 2. obj GEMM: barrier-free streaming (skips rows m%16==8)
    gemm_obj_stream<<<dim3(512), 256, 0, stream>>>(object_raw, WobjT, b_obj, obj_bf);

    // 3. act GEMM writes rows g*16+8
    gemm_dma<1, float><<<dim3(4, 16), 256, 0, stream>>>(
        action_raw, WactT, b_act, obj_bf, 512, 512, 512, 16, 8);

    // 4. graph stage: one wave per graph
    graph_mfma<<<dim3(2048), 64, 0, stream>>>(
        obj_bf, W1t, gc1_b, W2bf, gc2_b, W3t, gc3_b, W4bf, gc4_b, cbuf);

    // 5. c2 = relu(cbuf @ fc1_W + fc1_b)
    gemm_dma<1, ushort_t><<<dim3(8, 16), 256, 0, stream>>>(
        cbuf, fc1T, fc1_b, c2, 1024, 512, 1024, 1, 0);

    // 6. cmean = mean over T
    mean_c2<<<dim3(128), 256, 0, stream>>>(c2, cmean);

    // 7. out = cmean @ clf_W + clf_b (one block per column)
    clf_col<<<dim3(500), 256, 0, stream>>>(cmean, clf_W, clf_b, (float*)d_out);
}